// Round 2
// baseline (1184.455 us; speedup 1.0000x reference)
//
#include <hip/hip_runtime.h>
#include <hip/hip_cooperative_groups.h>
#include <math.h>

// ReDrafterHead: B=64, H=4096, D=512, G3=1536, V=32000, STEPS=4
// Round 6: single persistent cooperative kernel. 256 blocks x 512 threads,
// 1 block/CU, 27 grid.sync()s replace the 30-deep serial launch chain
// (~8 us/dispatch measured gap -> ~3 us/sync). Phase math identical to R5:
// pre-split bf16 hi/lo swizzled planes, global_load_lds identity staging,
// 2-phase double-buffered MFMA GEMM, 3-pass hi/lo accumulation.

namespace cg = cooperative_groups;

typedef __attribute__((ext_vector_type(8))) short short8;   // 8 bf16
typedef __attribute__((ext_vector_type(4))) float f32x4;

__device__ __forceinline__ unsigned short f2bf_rne(float x) {
    unsigned u = __float_as_uint(x);
    unsigned r = (u + 0x7fffu + ((u >> 16) & 1u)) >> 16;
    return (unsigned short)r;
}
// hi = truncate; lo = RNE of residual. 3-pass MFMA error ~2^-16 rel.
__device__ __forceinline__ void split2(float x, unsigned short& hi, unsigned short& lo) {
    unsigned u = __float_as_uint(x);
    hi = (unsigned short)(u >> 16);
    float r = x - __uint_as_float(u & 0xffff0000u);
    lo = f2bf_rne(r);
}

// store one element into swizzled bf16 hi/lo planes, row stride 512 elems.
__device__ __forceinline__ void store_plane(unsigned short* hiP, unsigned short* loP,
                                            int m, int d, float v) {
    int s = d >> 6, cl = (d >> 3) & 7, e = d & 7;
    int off = m * 512 + s * 64 + ((cl ^ (m & 7)) * 8) + e;
    unsigned short hi, lo; split2(v, hi, lo);
    hiP[off] = hi; loP[off] = lo;
}

__device__ __forceinline__ void gload16(const void* g, void* lds) {
    __builtin_amdgcn_global_load_lds(
        (const __attribute__((address_space(1))) unsigned int*)g,
        (__attribute__((address_space(3))) unsigned int*)lds, 16, 0, 0);
}

// ---------------------------------------------------------------------------
// Weight pre-split: W[N][K] fp32 -> swizzled bf16 planes, tile-major:
// ushort off = ((nt*(K/64) + ks)*128 + row)*64 + ((c8&7)^(row&7))*8
// ---------------------------------------------------------------------------
__device__ __forceinline__ void split_w_body(
    const float* __restrict__ W, unsigned short* __restrict__ H,
    unsigned short* __restrict__ L, size_t g, int kclog)
{
    int n  = (int)(g >> kclog);
    int c8 = (int)g & ((1 << kclog) - 1);
    const float* src = W + g * 8;
    float4 v0 = *(const float4*)src;
    float4 v1 = *(const float4*)(src + 4);
    unsigned short h[8], l[8];
    split2(v0.x,h[0],l[0]); split2(v0.y,h[1],l[1]); split2(v0.z,h[2],l[2]); split2(v0.w,h[3],l[3]);
    split2(v1.x,h[4],l[4]); split2(v1.y,h[5],l[5]); split2(v1.z,h[6],l[6]); split2(v1.w,h[7],l[7]);
    uint4 ph = make_uint4((unsigned)h[0]|((unsigned)h[1]<<16), (unsigned)h[2]|((unsigned)h[3]<<16),
                          (unsigned)h[4]|((unsigned)h[5]<<16), (unsigned)h[6]|((unsigned)h[7]<<16));
    uint4 pl = make_uint4((unsigned)l[0]|((unsigned)l[1]<<16), (unsigned)l[2]|((unsigned)l[3]<<16),
                          (unsigned)l[4]|((unsigned)l[5]<<16), (unsigned)l[6]|((unsigned)l[7]<<16));
    int nt = n >> 7, row = n & 127;
    int ksi = c8 >> 3;
    int slot = (c8 & 7) ^ (row & 7);
    int tpr = 1 << (kclog - 3);                 // tiles per row-tile = K/64
    size_t off = ((size_t)(nt * tpr + ksi) * 128 + row) * 64 + slot * 8;
    *(uint4*)(H + off) = ph;
    *(uint4*)(L + off) = pl;
}

// split hidden[64,4096] fp32 -> swizzled bf16 planes (row stride 8192 B)
__device__ __forceinline__ void split_a_body(
    const float* __restrict__ hidden, char* __restrict__ hidH,
    char* __restrict__ hidL, int g)
{
    int m = g >> 9;
    int cc = g & 511;
    int s = cc >> 3, cl = cc & 7;
    const float* src = hidden + m * 4096 + cc * 8;
    float4 v0 = *(const float4*)src;
    float4 v1 = *(const float4*)(src + 4);
    unsigned short h[8], l[8];
    split2(v0.x,h[0],l[0]); split2(v0.y,h[1],l[1]); split2(v0.z,h[2],l[2]); split2(v0.w,h[3],l[3]);
    split2(v1.x,h[4],l[4]); split2(v1.y,h[5],l[5]); split2(v1.z,h[6],l[6]); split2(v1.w,h[7],l[7]);
    uint4 ph = make_uint4((unsigned)h[0]|((unsigned)h[1]<<16), (unsigned)h[2]|((unsigned)h[3]<<16),
                          (unsigned)h[4]|((unsigned)h[5]<<16), (unsigned)h[6]|((unsigned)h[7]<<16));
    uint4 pl = make_uint4((unsigned)l[0]|((unsigned)l[1]<<16), (unsigned)l[2]|((unsigned)l[3]<<16),
                          (unsigned)l[4]|((unsigned)l[5]<<16), (unsigned)l[6]|((unsigned)l[7]<<16));
    int off = m * 8192 + s * 128 + ((cl ^ (m & 7)) * 16);
    *(uint4*)(hidH + off) = ph;
    *(uint4*)(hidL + off) = pl;
}

// ---------------------------------------------------------------------------
// MFMA GEMM, 512 threads (8 waves). C[0..63][n0..n0+127] over nk k-steps.
// ---------------------------------------------------------------------------
template<bool ARGMAX>
__device__ __forceinline__ void mfma_gemm(
    const char* __restrict__ AH, const char* __restrict__ AL, int AstrideB, int akk0,
    const unsigned short* __restrict__ BH, const unsigned short* __restrict__ BL,
    size_t btileU, int nk,
    float* __restrict__ C, int ldc, int n0,
    unsigned short (*AsH)[4096], unsigned short (*AsL)[4096],
    unsigned short (*BsH)[8192], unsigned short (*BsL)[8192],
    float* __restrict__ pval, int* __restrict__ pidx, int bx)
{
    const int tid  = threadIdx.x;
    const int wv   = tid >> 6;
    const int lane = tid & 63;
    const int lr   = lane & 15;
    const int lh   = lane >> 4;
    const int m    = tid >> 3;
    const int cp   = tid & 7;

    f32x4 acc[4];
#pragma unroll
    for (int i = 0; i < 4; ++i) acc[i] = (f32x4){0.f, 0.f, 0.f, 0.f};

    auto stage = [&](int t, int p) {
        const int ka = (akk0 + t * 64) * 2;
        gload16(AH + m * AstrideB + ka + cp * 16, (char*)AsH[p] + wv * 1024);
        gload16(AL + m * AstrideB + ka + cp * 16, (char*)AsL[p] + wv * 1024);
        const char* bH = (const char*)BH + (btileU + (size_t)t * 8192) * 2;
        const char* bL = (const char*)BL + (btileU + (size_t)t * 8192) * 2;
        gload16(bH + wv * 2048 +        lane * 16, (char*)BsH[p] + wv * 2048);
        gload16(bH + wv * 2048 + 1024 + lane * 16, (char*)BsH[p] + wv * 2048 + 1024);
        gload16(bL + wv * 2048 +        lane * 16, (char*)BsL[p] + wv * 2048);
        gload16(bL + wv * 2048 + 1024 + lane * 16, (char*)BsL[p] + wv * 2048 + 1024);
    };

    stage(0, 0);
    __syncthreads();

    for (int t = 0; t < nk; ++t) {
        const int p = t & 1;
        if (t + 1 < nk) stage(t + 1, p ^ 1);
#pragma unroll
        for (int kk2 = 0; kk2 < 2; ++kk2) {
            int aoff = lr * 64 + (((kk2 * 4 + lh) ^ (lr & 7)) * 8);
            short8 ah[4], al[4];
#pragma unroll
            for (int mt = 0; mt < 4; ++mt) {
                ah[mt] = *(const short8*)(AsH[p] + mt * 1024 + aoff);
                al[mt] = *(const short8*)(AsL[p] + mt * 1024 + aoff);
            }
            int brow = wv * 16 + lr;
            int boff = brow * 64 + (((kk2 * 4 + lh) ^ (brow & 7)) * 8);
            short8 bh = *(const short8*)(BsH[p] + boff);
            short8 bl = *(const short8*)(BsL[p] + boff);
#pragma unroll
            for (int mt = 0; mt < 4; ++mt) {
                acc[mt] = __builtin_amdgcn_mfma_f32_16x16x32_bf16(ah[mt], bh, acc[mt], 0, 0, 0);
                acc[mt] = __builtin_amdgcn_mfma_f32_16x16x32_bf16(ah[mt], bl, acc[mt], 0, 0, 0);
                acc[mt] = __builtin_amdgcn_mfma_f32_16x16x32_bf16(al[mt], bh, acc[mt], 0, 0, 0);
            }
        }
        __syncthreads();
    }

#pragma unroll
    for (int mt = 0; mt < 4; ++mt)
#pragma unroll
        for (int i = 0; i < 4; ++i) {
            int mm = mt * 16 + lh * 4 + i;
            C[mm * ldc + n0 + wv * 16 + lr] = acc[mt][i];
        }

    if (ARGMAX) {
        float* sv = (float*)&AsH[0][0];
        int*   sc = (int*)&AsL[0][0];
#pragma unroll
        for (int mt = 0; mt < 4; ++mt)
#pragma unroll
            for (int i = 0; i < 4; ++i) {
                float v = acc[mt][i];
                int   c = n0 + wv * 16 + lr;
#pragma unroll
                for (int msk = 1; msk < 16; msk <<= 1) {
                    float ov = __shfl_xor(v, msk, 64);
                    int   oc = __shfl_xor(c, msk, 64);
                    if (ov > v || (ov == v && oc < c)) { v = ov; c = oc; }
                }
                if (lr == 0) {
                    int row = mt * 16 + lh * 4 + i;
                    sv[wv * 64 + row] = v;
                    sc[wv * 64 + row] = c;
                }
            }
        __syncthreads();
        if (tid < 64) {
            float v = sv[tid]; int c = sc[tid];
#pragma unroll
            for (int w = 1; w < 8; ++w) {
                float ov = sv[w * 64 + tid]; int oc = sc[w * 64 + tid];
                if (ov > v) { v = ov; c = oc; }   // ascending col order -> first-occurrence
            }
            pval[bx * 64 + tid] = v;
            pidx[bx * 64 + tid] = c;
        }
        __syncthreads();   // protect LDS scratch before any reuse
    }
}

struct KP {
    const float *hidden, *in_w, *in_b, *w_ih0, *w_hh0, *b_ih0, *b_hh0,
                *w_ih1, *w_hh1, *b_ih1, *b_hh1, *embed, *out_w;
    float* out;
    char* ws;
};

// ---------------------------------------------------------------------------
// The persistent kernel. grid = 256 x 512, LDS 96 KiB -> 1 block/CU.
// ---------------------------------------------------------------------------
__global__ __launch_bounds__(512) void k_persistent(KP p)
{
    cg::grid_group grid = cg::this_grid();

    __shared__ alignas(16) unsigned short AsH[2][4096];
    __shared__ alignas(16) unsigned short AsL[2][4096];
    __shared__ alignas(16) unsigned short BsH[2][8192];
    __shared__ alignas(16) unsigned short BsL[2][8192];   // 96 KiB

    const int bx  = blockIdx.x;
    const int tid = threadIdx.x;
    char* ws = p.ws;

    // ws layout (bytes) — ~98.5 MiB of 256 MiB workspace
    float* hA  = (float*)(ws + 0);                          // 131072
    float* hB  = (float*)(ws + 131072);                     // 131072
    unsigned short* xH  = (unsigned short*)(ws + 262144);   // 65536 each
    unsigned short* xL  = (unsigned short*)(ws + 327680);
    unsigned short* hAH = (unsigned short*)(ws + 393216);
    unsigned short* hAL = (unsigned short*)(ws + 458752);
    unsigned short* hBH = (unsigned short*)(ws + 524288);
    unsigned short* hBL = (unsigned short*)(ws + 589824);
    char* hidH = ws + 655360;                               // 524288
    char* hidL = ws + 1179648;                              // 524288
    float* gip = (float*)(ws + 1703936);                    // 8*98304*4 = 3145728
    float* ghp = (float*)(ws + 4849664);                    // 3145728
    float* pval = (float*)(ws + 7995392);                   // 64000
    int*   pidx = (int*)  (ws + 8059392);                   // 64000
    float* ipart = (float*)(ws + 8388608);                  // 64*131072 B = 8388608
    unsigned short* owH = (unsigned short*)(ws + 16777216); // 32768000
    unsigned short* owL = (unsigned short*)(ws + 49545216); // 32768000
    unsigned short* gwH = (unsigned short*)(ws + 82313216); // 6291456
    unsigned short* gwL = (unsigned short*)(ws + 88604672); // 6291456
    unsigned short* inH = (unsigned short*)(ws + 94896128); // 4194304
    unsigned short* inL = (unsigned short*)(ws + 99090432); // 4194304

    const size_t gt = (size_t)bx * 512 + tid;               // 131072 threads

    // ---- P0a: split in_w (512x4096, kclog=9) + hidden ----
    for (size_t g = gt; g < 262144; g += 131072)
        split_w_body(p.in_w, inH, inL, g, 9);
    if (gt < 32768)
        split_a_body(p.hidden, hidH, hidL, (int)gt);
    grid.sync();

    // ---- P0b: inproj GEMM (K-split 64, 1 k-step/block) hides under the
    //           big out_w + gru-weight splits (independent work) ----
    {
        int nt = bx & 3, ks = bx >> 2;                      // ks 0..63
        mfma_gemm<false>(hidH, hidL, 8192, ks * 64,
                         inH, inL, (size_t)(nt * 64 + ks) * 8192, 1,
                         ipart + ks * 32768, 512, nt * 128,
                         AsH, AsL, BsH, BsL, nullptr, nullptr, 0);
    }
    for (size_t g = gt; g < 2048000; g += 131072)           // out_w 32000x512
        split_w_body(p.out_w, owH, owL, g, 6);
    for (size_t g = gt; g < 393216; g += 131072) {          // 4 GRU mats
        int mat = (int)(g / 98304);
        const float* W = mat == 0 ? p.w_ih0 : mat == 1 ? p.w_hh0
                       : mat == 2 ? p.w_ih1 : p.w_hh1;
        split_w_body(W, gwH + (size_t)mat * 786432, gwL + (size_t)mat * 786432,
                     g % 98304, 6);
    }
    grid.sync();

    // ---- P0c: reduce inproj partials (64 blocks) ----
    if (bx < 64) {
        int i = bx * 512 + tid;                             // < 32768
        int b = i >> 9, d = i & 511;
        float s = p.in_b[d];
        for (int ks = 0; ks < 64; ++ks) s += ipart[ks * 32768 + i];
        hA[i] = s; hB[i] = s;
        store_plane(hAH, hAL, b, d, s);
        store_plane(hBH, hBL, b, d, s);
        store_plane(xH,  xL,  b, d, 0.f);
    }
    grid.sync();

    // ---- step loop ----
    for (int step = 0; step < 4; ++step) {
#pragma unroll 1
        for (int layer = 0; layer < 2; ++layer) {
            // gates: 192 blocks = 12 nt x 8 ks x 2 mat, 1 k-step each
            if (bx < 192) {
                int nt = bx % 12, ks = (bx / 12) & 7, mat = bx / 96;
                const char* AH_;
                const char* AL_;
                if (layer == 0) { AH_ = mat ? (char*)hAH : (char*)xH;
                                  AL_ = mat ? (char*)hAL : (char*)xL; }
                else            { AH_ = mat ? (char*)hBH : (char*)hAH;
                                  AL_ = mat ? (char*)hBL : (char*)hAL; }
                float* C = (mat ? ghp : gip) + ks * 98304;
                size_t btile = ((size_t)(layer * 2 + mat) * 96 + nt * 8 + ks) * 8192;
                mfma_gemm<false>(AH_, AL_, 1024, ks * 64,
                                 gwH, gwL, btile, 1,
                                 C, 1536, nt * 128,
                                 AsH, AsL, BsH, BsL, nullptr, nullptr, 0);
            }
            grid.sync();

            // combine: 64 blocks, sums 8 K-split partials
            if (bx < 64) {
                int i = bx * 512 + tid;                     // < 32768
                int b = i >> 9, d = i & 511;
                const float* bi = layer ? p.b_ih1 : p.b_ih0;
                const float* bh2 = layer ? p.b_hh1 : p.b_hh0;
                float ir = bi[d], iz = bi[d + 512], inn = bi[d + 1024];
                float hr = bh2[d], hz = bh2[d + 512], hn = bh2[d + 1024];
                int base = b * 1536 + d;
#pragma unroll
                for (int ks = 0; ks < 8; ++ks) {
                    const float* gi = gip + ks * 98304 + base;
                    const float* gh = ghp + ks * 98304 + base;
                    ir += gi[0]; iz += gi[512]; inn += gi[1024];
                    hr += gh[0]; hz += gh[512]; hn  += gh[1024];
                }
                float r = 1.f / (1.f + expf(-(ir + hr)));
                float z = 1.f / (1.f + expf(-(iz + hz)));
                float n = tanhf(inn + r * hn);
                float* h = layer ? hB : hA;
                float hv = (1.f - z) * n + z * h[i];
                h[i] = hv;
                store_plane(layer ? hBH : hAH, layer ? hBL : hAL, b, d, hv);
            }
            grid.sync();
        }

        // logits + per-block argmax partials: 250 blocks x 8 k-steps
        if (bx < 250) {
            mfma_gemm<true>((const char*)hBH, (const char*)hBL, 1024, 0,
                            owH, owL, (size_t)bx * 8 * 8192, 8,
                            p.out + step * 32000, 128000, bx * 128,
                            AsH, AsL, BsH, BsL, pval, pidx, bx);
        }
        grid.sync();

        // reduce 250 argmax partials + embed gather -> x planes (64 blocks)
        if (bx < 64) {
            float* sv = (float*)&AsH[0][0];                 // 512 floats
            int*   sc = (int*)&AsL[0][0];
            float v = -3.4e38f; int c = 0x7fffffff;
            if (tid < 250) { v = pval[tid * 64 + bx]; c = pidx[tid * 64 + bx]; }
            sv[tid] = v; sc[tid] = c;
            __syncthreads();
            for (int s = 256; s > 0; s >>= 1) {
                if (tid < s) {
                    float ov = sv[tid + s]; int oc = sc[tid + s];
                    if (ov > sv[tid] || (ov == sv[tid] && oc < sc[tid])) {
                        sv[tid] = ov; sc[tid] = oc;
                    }
                }
                __syncthreads();
            }
            int tok = sc[0];
            store_plane(xH, xL, bx, tid, p.embed[(size_t)tok * 512 + tid]);
        }
        grid.sync();
    }
}

// ---------------------------------------------------------------------------
extern "C" void kernel_launch(void* const* d_in, const int* in_sizes, int n_in,
                              void* d_out, int out_size, void* d_ws, size_t ws_size,
                              hipStream_t stream)
{
    KP p;
    p.hidden = (const float*)d_in[0];
    p.in_w   = (const float*)d_in[1];
    p.in_b   = (const float*)d_in[2];
    p.w_ih0  = (const float*)d_in[3];
    p.w_hh0  = (const float*)d_in[4];
    p.b_ih0  = (const float*)d_in[5];
    p.b_hh0  = (const float*)d_in[6];
    p.w_ih1  = (const float*)d_in[7];
    p.w_hh1  = (const float*)d_in[8];
    p.b_ih1  = (const float*)d_in[9];
    p.b_hh1  = (const float*)d_in[10];
    p.embed  = (const float*)d_in[11];
    p.out_w  = (const float*)d_in[12];
    p.out    = (float*)d_out;
    p.ws     = (char*)d_ws;

    void* args[] = { (void*)&p };
    hipLaunchCooperativeKernel(k_persistent, dim3(256), dim3(512), args, 0, stream);
}

// Round 3
// 370.444 us; speedup vs baseline: 3.1974x; 3.1974x over previous
//
#include <hip/hip_runtime.h>
#include <math.h>

// ReDrafterHead: B=64, H=4096, D=512, G3=1536, V=32000, STEPS=4
// Round 7: back to multi-kernel (grid.sync measured ~30us/sync in R6 -> dead
// end). Dispatch count 30 -> 23: argmax-reduce + embed gather fused into the
// gates-mat0 blocks (x planes + k_reduce_embed eliminated); gh1 (hB@w_hh1)
// hoisted into the first gates dispatch of each step; prologue collapsed to
// 3 dispatches (one grid-stride split of all weights, inproj K-split 64,
// reduce). GEMM core / layouts / 3-pass numerics identical to R5.

typedef __attribute__((ext_vector_type(8))) short short8;   // 8 bf16
typedef __attribute__((ext_vector_type(4))) float f32x4;

__device__ __forceinline__ unsigned short f2bf_rne(float x) {
    unsigned u = __float_as_uint(x);
    unsigned r = (u + 0x7fffu + ((u >> 16) & 1u)) >> 16;
    return (unsigned short)r;
}
// hi = truncate; lo = RNE of residual. 3-pass MFMA error ~2^-16 rel.
__device__ __forceinline__ void split2(float x, unsigned short& hi, unsigned short& lo) {
    unsigned u = __float_as_uint(x);
    hi = (unsigned short)(u >> 16);
    float r = x - __uint_as_float(u & 0xffff0000u);
    lo = f2bf_rne(r);
}

// store one element into swizzled bf16 hi/lo planes, row stride 512 elems.
__device__ __forceinline__ void store_plane(unsigned short* hiP, unsigned short* loP,
                                            int m, int d, float v) {
    int s = d >> 6, cl = (d >> 3) & 7, e = d & 7;
    int off = m * 512 + s * 64 + ((cl ^ (m & 7)) * 8) + e;
    unsigned short hi, lo; split2(v, hi, lo);
    hiP[off] = hi; loP[off] = lo;
}

__device__ __forceinline__ void gload16(const void* g, void* lds) {
    __builtin_amdgcn_global_load_lds(
        (const __attribute__((address_space(1))) unsigned int*)g,
        (__attribute__((address_space(3))) unsigned int*)lds, 16, 0, 0);
}

// ---------------------------------------------------------------------------
// Weight pre-split: W[N][K] fp32 -> swizzled bf16 planes, tile-major:
// ushort off = ((nt*(K/64) + ks)*128 + row)*64 + ((c8&7)^(row&7))*8
// ---------------------------------------------------------------------------
__device__ __forceinline__ void split_w_body(
    const float* __restrict__ W, unsigned short* __restrict__ H,
    unsigned short* __restrict__ L, size_t g, int kclog)
{
    int n  = (int)(g >> kclog);
    int c8 = (int)g & ((1 << kclog) - 1);
    const float* src = W + g * 8;
    float4 v0 = *(const float4*)src;
    float4 v1 = *(const float4*)(src + 4);
    unsigned short h[8], l[8];
    split2(v0.x,h[0],l[0]); split2(v0.y,h[1],l[1]); split2(v0.z,h[2],l[2]); split2(v0.w,h[3],l[3]);
    split2(v1.x,h[4],l[4]); split2(v1.y,h[5],l[5]); split2(v1.z,h[6],l[6]); split2(v1.w,h[7],l[7]);
    uint4 ph = make_uint4((unsigned)h[0]|((unsigned)h[1]<<16), (unsigned)h[2]|((unsigned)h[3]<<16),
                          (unsigned)h[4]|((unsigned)h[5]<<16), (unsigned)h[6]|((unsigned)h[7]<<16));
    uint4 pl = make_uint4((unsigned)l[0]|((unsigned)l[1]<<16), (unsigned)l[2]|((unsigned)l[3]<<16),
                          (unsigned)l[4]|((unsigned)l[5]<<16), (unsigned)l[6]|((unsigned)l[7]<<16));
    int nt = n >> 7, row = n & 127;
    int ksi = c8 >> 3;
    int slot = (c8 & 7) ^ (row & 7);
    int tpr = 1 << (kclog - 3);                 // tiles per row-tile = K/64
    size_t off = ((size_t)(nt * tpr + ksi) * 128 + row) * 64 + slot * 8;
    *(uint4*)(H + off) = ph;
    *(uint4*)(L + off) = pl;
}

// split hidden[64,4096] fp32 -> swizzled bf16 planes (row stride 8192 B)
__device__ __forceinline__ void split_a_body(
    const float* __restrict__ hidden, char* __restrict__ hidH,
    char* __restrict__ hidL, int g)
{
    int m = g >> 9;
    int cc = g & 511;
    int s = cc >> 3, cl = cc & 7;
    const float* src = hidden + m * 4096 + cc * 8;
    float4 v0 = *(const float4*)src;
    float4 v1 = *(const float4*)(src + 4);
    unsigned short h[8], l[8];
    split2(v0.x,h[0],l[0]); split2(v0.y,h[1],l[1]); split2(v0.z,h[2],l[2]); split2(v0.w,h[3],l[3]);
    split2(v1.x,h[4],l[4]); split2(v1.y,h[5],l[5]); split2(v1.z,h[6],l[6]); split2(v1.w,h[7],l[7]);
    uint4 ph = make_uint4((unsigned)h[0]|((unsigned)h[1]<<16), (unsigned)h[2]|((unsigned)h[3]<<16),
                          (unsigned)h[4]|((unsigned)h[5]<<16), (unsigned)h[6]|((unsigned)h[7]<<16));
    uint4 pl = make_uint4((unsigned)l[0]|((unsigned)l[1]<<16), (unsigned)l[2]|((unsigned)l[3]<<16),
                          (unsigned)l[4]|((unsigned)l[5]<<16), (unsigned)l[6]|((unsigned)l[7]<<16));
    int off = m * 8192 + s * 128 + ((cl ^ (m & 7)) * 16);
    *(uint4*)(hidH + off) = ph;
    *(uint4*)(hidL + off) = pl;
}

// ---------------------------------------------------------------------------
// Shared MFMA inner core: one 64-k tile from LDS buffers into acc[4].
// ---------------------------------------------------------------------------
__device__ __forceinline__ void mfma_core(
    const unsigned short* __restrict__ AsH0, const unsigned short* __restrict__ AsL0,
    const unsigned short* __restrict__ BsH0, const unsigned short* __restrict__ BsL0,
    int wv, int lr, int lh, f32x4* acc)
{
#pragma unroll
    for (int kk2 = 0; kk2 < 2; ++kk2) {
        int aoff = lr * 64 + (((kk2 * 4 + lh) ^ (lr & 7)) * 8);
        short8 ah[4], al[4];
#pragma unroll
        for (int mt = 0; mt < 4; ++mt) {
            ah[mt] = *(const short8*)(AsH0 + mt * 1024 + aoff);
            al[mt] = *(const short8*)(AsL0 + mt * 1024 + aoff);
        }
        int brow = wv * 16 + lr;
        int boff = brow * 64 + (((kk2 * 4 + lh) ^ (brow & 7)) * 8);
        short8 bh = *(const short8*)(BsH0 + boff);
        short8 bl = *(const short8*)(BsL0 + boff);
#pragma unroll
        for (int mt = 0; mt < 4; ++mt) {
            acc[mt] = __builtin_amdgcn_mfma_f32_16x16x32_bf16(ah[mt], bh, acc[mt], 0, 0, 0);
            acc[mt] = __builtin_amdgcn_mfma_f32_16x16x32_bf16(ah[mt], bl, acc[mt], 0, 0, 0);
            acc[mt] = __builtin_amdgcn_mfma_f32_16x16x32_bf16(al[mt], bh, acc[mt], 0, 0, 0);
        }
    }
}

__device__ __forceinline__ void epilogue_write(
    float* __restrict__ C, int ldc, int n0, int wv, int lr, int lh, const f32x4* acc)
{
#pragma unroll
    for (int mt = 0; mt < 4; ++mt)
#pragma unroll
        for (int i = 0; i < 4; ++i) {
            int mm = mt * 16 + lh * 4 + i;
            C[mm * ldc + n0 + wv * 16 + lr] = acc[mt][i];
        }
}

// ---------------------------------------------------------------------------
// MFMA GEMM, 512 threads (8 waves). C[0..63][n0..n0+127] over nk k-steps.
// A: pre-split swizzled bf16 planes; B: tiled planes, identity gload_lds copy.
// ---------------------------------------------------------------------------
template<bool ARGMAX>
__device__ __forceinline__ void mfma_gemm(
    const char* __restrict__ AH, const char* __restrict__ AL, int AstrideB, int akk0,
    const unsigned short* __restrict__ BH, const unsigned short* __restrict__ BL,
    size_t btileU, int nk,
    float* __restrict__ C, int ldc, int n0,
    unsigned short (*AsH)[4096], unsigned short (*AsL)[4096],
    unsigned short (*BsH)[8192], unsigned short (*BsL)[8192],
    float* __restrict__ pval, int* __restrict__ pidx, int bx)
{
    const int tid  = threadIdx.x;
    const int wv   = tid >> 6;
    const int lane = tid & 63;
    const int lr   = lane & 15;
    const int lh   = lane >> 4;
    const int m    = tid >> 3;
    const int cp   = tid & 7;

    f32x4 acc[4];
#pragma unroll
    for (int i = 0; i < 4; ++i) acc[i] = (f32x4){0.f, 0.f, 0.f, 0.f};

    auto stage = [&](int t, int p) {
        const int ka = (akk0 + t * 64) * 2;
        gload16(AH + m * AstrideB + ka + cp * 16, (char*)AsH[p] + wv * 1024);
        gload16(AL + m * AstrideB + ka + cp * 16, (char*)AsL[p] + wv * 1024);
        const char* bH = (const char*)BH + (btileU + (size_t)t * 8192) * 2;
        const char* bL = (const char*)BL + (btileU + (size_t)t * 8192) * 2;
        gload16(bH + wv * 2048 +        lane * 16, (char*)BsH[p] + wv * 2048);
        gload16(bH + wv * 2048 + 1024 + lane * 16, (char*)BsH[p] + wv * 2048 + 1024);
        gload16(bL + wv * 2048 +        lane * 16, (char*)BsL[p] + wv * 2048);
        gload16(bL + wv * 2048 + 1024 + lane * 16, (char*)BsL[p] + wv * 2048 + 1024);
    };

    stage(0, 0);
    __syncthreads();

    for (int t = 0; t < nk; ++t) {
        const int p = t & 1;
        if (t + 1 < nk) stage(t + 1, p ^ 1);   // prefetch hides under MFMA
        mfma_core(AsH[p], AsL[p], BsH[p], BsL[p], wv, lr, lh, acc);
        __syncthreads();
    }

    epilogue_write(C, ldc, n0, wv, lr, lh, acc);

    if (ARGMAX) {
        float* sv = (float*)&AsH[0][0];
        int*   sc = (int*)&AsL[0][0];
#pragma unroll
        for (int mt = 0; mt < 4; ++mt)
#pragma unroll
            for (int i = 0; i < 4; ++i) {
                float v = acc[mt][i];
                int   c = n0 + wv * 16 + lr;
#pragma unroll
                for (int msk = 1; msk < 16; msk <<= 1) {
                    float ov = __shfl_xor(v, msk, 64);
                    int   oc = __shfl_xor(c, msk, 64);
                    if (ov > v || (ov == v && oc < c)) { v = ov; c = oc; }
                }
                if (lr == 0) {
                    int row = mt * 16 + lh * 4 + i;
                    sv[wv * 64 + row] = v;
                    sc[wv * 64 + row] = c;
                }
            }
        __syncthreads();
        if (tid < 64) {
            float v = sv[tid]; int c = sc[tid];
#pragma unroll
            for (int w = 1; w < 8; ++w) {
                float ov = sv[w * 64 + tid]; int oc = sc[w * 64 + tid];
                if (ov > v) { v = ov; c = oc; }   // ascending col -> first-occurrence
            }
            pval[bx * 64 + tid] = v;
            pidx[bx * 64 + tid] = c;
        }
    }
}

#define DECLARE_LDS() \
    __shared__ alignas(16) unsigned short AsH[2][4096]; \
    __shared__ alignas(16) unsigned short AsL[2][4096]; \
    __shared__ alignas(16) unsigned short BsH[2][8192]; \
    __shared__ alignas(16) unsigned short BsL[2][8192];   /* 96 KiB total */

// ---------------------------------------------------------------------------
// P1: one grid-stride dispatch splits out_w + 4 GRU mats + in_w + hidden.
// ---------------------------------------------------------------------------
__global__ __launch_bounds__(512) void k_split_all(
    const float* __restrict__ out_w, const float* __restrict__ w_ih0,
    const float* __restrict__ w_hh0, const float* __restrict__ w_ih1,
    const float* __restrict__ w_hh1, const float* __restrict__ in_w,
    const float* __restrict__ hidden,
    unsigned short* __restrict__ owH, unsigned short* __restrict__ owL,
    unsigned short* __restrict__ gwH, unsigned short* __restrict__ gwL,
    unsigned short* __restrict__ inH, unsigned short* __restrict__ inL,
    char* __restrict__ hidH, char* __restrict__ hidL)
{
    size_t gt = (size_t)blockIdx.x * 512 + threadIdx.x;    // 131072 threads
    for (size_t u = gt; u < 2736128; u += 131072) {
        if (u < 2048000) {
            split_w_body(out_w, owH, owL, u, 6);
        } else if (u < 2441216) {
            size_t g = u - 2048000;
            int mat = (int)(g / 98304);
            const float* W = mat == 0 ? w_ih0 : mat == 1 ? w_hh0
                           : mat == 2 ? w_ih1 : w_hh1;
            split_w_body(W, gwH + (size_t)mat * 786432, gwL + (size_t)mat * 786432,
                         g % 98304, 6);
        } else if (u < 2703360) {
            split_w_body(in_w, inH, inL, u - 2441216, 9);
        } else {
            split_a_body(hidden, hidH, hidL, (int)(u - 2703360));
        }
    }
}

// ---------------------------------------------------------------------------
// P2: inproj, K-split 64: 256 blocks (4 nt x 64 ks), 1 k-step each.
// ---------------------------------------------------------------------------
__global__ __launch_bounds__(512) void k_inproj(
    const char* __restrict__ hidH, const char* __restrict__ hidL,
    const unsigned short* __restrict__ inH, const unsigned short* __restrict__ inL,
    float* __restrict__ ipart)
{
    DECLARE_LDS();
    int nt = blockIdx.x & 3;
    int ks = blockIdx.x >> 2;                 // 0..63
    mfma_gemm<false>(hidH, hidL, 8192, ks * 64,
                     inH, inL, (size_t)(nt * 64 + ks) * 8192, 1,
                     ipart + ks * 32768, 512, nt * 128,
                     AsH, AsL, BsH, BsL, nullptr, nullptr, 0);
}

// P3: reduce 64 inproj partials + bias -> hA, hB (fp32 + planes)
__global__ __launch_bounds__(512) void k_reduce_inproj(
    const float* __restrict__ ipart, const float* __restrict__ bias,
    float* __restrict__ hA, float* __restrict__ hB,
    unsigned short* hAH, unsigned short* hAL,
    unsigned short* hBH, unsigned short* hBL)
{
    int i = blockIdx.x * 512 + threadIdx.x;   // < 32768
    int b = i >> 9;
    int d = i & 511;
    float s = bias[d];
#pragma unroll 8
    for (int ks = 0; ks < 64; ++ks) s += ipart[ks * 32768 + i];
    hA[i] = s;
    hB[i] = s;
    store_plane(hAH, hAL, b, d, s);
    store_plane(hBH, hBL, b, d, s);
}

// ---------------------------------------------------------------------------
// S1: 240 blocks.
//  bx<96:    gi0 = x @ w_ih0^T  (K-split 8) — x computed in-kernel from the
//            previous step's argmax partials + embed (step 0: x=0 -> zeros).
//  96..191:  gh0 = hA @ w_hh0^T (K-split 8)
//  192..239: gh1 = hB @ w_hh1^T (K-split 4, 2 k-steps; needed only at S4)
// ---------------------------------------------------------------------------
__global__ __launch_bounds__(512) void k_gates3(
    int step,
    const float* __restrict__ pval, const int* __restrict__ pidx,
    const float* __restrict__ embed,
    const char* __restrict__ hAH, const char* __restrict__ hAL,
    const char* __restrict__ hBH, const char* __restrict__ hBL,
    const unsigned short* __restrict__ gwH, const unsigned short* __restrict__ gwL,
    float* __restrict__ gi0, float* __restrict__ gh0, float* __restrict__ gh1)
{
    DECLARE_LDS();
    const int bx  = blockIdx.x;
    const int tid = threadIdx.x;

    if (bx < 96) {
        int nt = bx % 12, ks = bx / 12;
        float* C = gi0 + ks * 98304;
        if (step == 0) {
            // x = 0 -> gi0 partial tile = 0
            float4 z = make_float4(0.f, 0.f, 0.f, 0.f);
            for (int q = tid; q < 2048; q += 512) {
                int r = q >> 4, cq = q & 15;
                *(float4*)(C + r * 1536 + nt * 128 + cq * 4) = z;
            }
            return;
        }
        const int wv = tid >> 6, lane = tid & 63, lr = lane & 15, lh = lane >> 4;
        // 1) issue B stage (weights tile) into buffer 0
        size_t btileU = ((size_t)nt * 8 + ks) * 8192;      // mat 0 = w_ih0
        const char* bH = (const char*)gwH + btileU * 2;
        const char* bL = (const char*)gwL + btileU * 2;
        gload16(bH + wv * 2048 +        lane * 16, (char*)BsH[0] + wv * 2048);
        gload16(bH + wv * 2048 + 1024 + lane * 16, (char*)BsH[0] + wv * 2048 + 1024);
        gload16(bL + wv * 2048 +        lane * 16, (char*)BsL[0] + wv * 2048);
        gload16(bL + wv * 2048 + 1024 + lane * 16, (char*)BsL[0] + wv * 2048 + 1024);
        // 2) argmax over 250 partials (8 threads per batch row)
        int r = tid >> 3, j0 = tid & 7;
        float v = -3.4e38f; int c = 0x7fffffff;
        for (int j = j0; j < 250; j += 8) {
            float ov = pval[j * 64 + r]; int oc = pidx[j * 64 + r];
            if (ov > v || (ov == v && oc < c)) { v = ov; c = oc; }
        }
#pragma unroll
        for (int msk = 1; msk < 8; msk <<= 1) {
            float ov = __shfl_xor(v, msk, 64);
            int   oc = __shfl_xor(c, msk, 64);
            if (ov > v || (ov == v && oc < c)) { v = ov; c = oc; }
        }
        int* stok = (int*)AsH[1];                          // buffer 1 unused (nk=1)
        if (j0 == 0) stok[r] = c;
        __syncthreads();                                   // tokens + B tile ready
        // 3) x tile: embed gather + split2, written directly in A-LDS layout
        {
            int mm = tid >> 3, cp = tid & 7;
            int tok = stok[mm];
            const float* src = embed + (size_t)tok * 512 + ks * 64 + cp * 8;
            float4 v0 = *(const float4*)src;
            float4 v1 = *(const float4*)(src + 4);
            unsigned short h[8], l[8];
            split2(v0.x,h[0],l[0]); split2(v0.y,h[1],l[1]); split2(v0.z,h[2],l[2]); split2(v0.w,h[3],l[3]);
            split2(v1.x,h[4],l[4]); split2(v1.y,h[5],l[5]); split2(v1.z,h[6],l[6]); split2(v1.w,h[7],l[7]);
            uint4 ph = make_uint4((unsigned)h[0]|((unsigned)h[1]<<16), (unsigned)h[2]|((unsigned)h[3]<<16),
                                  (unsigned)h[4]|((unsigned)h[5]<<16), (unsigned)h[6]|((unsigned)h[7]<<16));
            uint4 pl = make_uint4((unsigned)l[0]|((unsigned)l[1]<<16), (unsigned)l[2]|((unsigned)l[3]<<16),
                                  (unsigned)l[4]|((unsigned)l[5]<<16), (unsigned)l[6]|((unsigned)l[7]<<16));
            int off = mm * 64 + ((cp ^ (mm & 7)) * 8);
            *(uint4*)(AsH[0] + off) = ph;
            *(uint4*)(AsL[0] + off) = pl;
        }
        __syncthreads();
        // 4) MFMA + epilogue
        f32x4 acc[4];
#pragma unroll
        for (int i = 0; i < 4; ++i) acc[i] = (f32x4){0.f, 0.f, 0.f, 0.f};
        mfma_core(AsH[0], AsL[0], BsH[0], BsL[0], wv, lr, lh, acc);
        epilogue_write(C, 1536, nt * 128, wv, lr, lh, acc);
    } else if (bx < 192) {
        int idx = bx - 96;
        int nt = idx % 12, ks = idx / 12;
        size_t btile = ((size_t)96 + nt * 8 + ks) * 8192;  // mat 1 = w_hh0
        mfma_gemm<false>((const char*)hAH, (const char*)hAL, 1024, ks * 64,
                         gwH, gwL, btile, 1,
                         gh0 + ks * 98304, 1536, nt * 128,
                         AsH, AsL, BsH, BsL, nullptr, nullptr, 0);
    } else {
        int idx = bx - 192;
        int nt = idx % 12, ks2 = idx / 12;                 // 0..3
        size_t btile = ((size_t)288 + nt * 8 + ks2 * 2) * 8192;  // mat 3 = w_hh1
        mfma_gemm<false>((const char*)hBH, (const char*)hBL, 1024, ks2 * 128,
                         gwH, gwL, btile, 2,
                         gh1 + ks2 * 98304, 1536, nt * 128,
                         AsH, AsL, BsH, BsL, nullptr, nullptr, 0);
    }
}

// ---------------------------------------------------------------------------
// S3: gi1 = hA' @ w_ih1^T (K-split 8): 96 blocks.
// ---------------------------------------------------------------------------
__global__ __launch_bounds__(512) void k_gates1(
    const char* __restrict__ hAH, const char* __restrict__ hAL,
    const unsigned short* __restrict__ gwH, const unsigned short* __restrict__ gwL,
    float* __restrict__ gi1)
{
    DECLARE_LDS();
    int nt = blockIdx.x % 12, ks = blockIdx.x / 12;
    size_t btile = ((size_t)192 + nt * 8 + ks) * 8192;     // mat 2 = w_ih1
    mfma_gemm<false>((const char*)hAH, (const char*)hAL, 1024, ks * 64,
                     gwH, gwL, btile, 1,
                     gi1 + ks * 98304, 1536, nt * 128,
                     AsH, AsL, BsH, BsL, nullptr, nullptr, 0);
}

// ---------------------------------------------------------------------------
// combine: sum K-split partials + biases, GRU cell, write h + planes.
// ---------------------------------------------------------------------------
template<int NGI, int NGH>
__global__ __launch_bounds__(512) void k_combine(
    const float* __restrict__ gi, const float* __restrict__ gh,
    const float* __restrict__ b_ih, const float* __restrict__ b_hh,
    float* __restrict__ h, unsigned short* hH, unsigned short* hL)
{
    int i = blockIdx.x * 512 + threadIdx.x;   // < 32768
    int b = i >> 9;
    int d = i & 511;
    int base = b * 1536 + d;
    float ir = b_ih[d], iz = b_ih[d + 512], inn = b_ih[d + 1024];
    float hr = b_hh[d], hz = b_hh[d + 512], hn = b_hh[d + 1024];
#pragma unroll
    for (int ks = 0; ks < NGI; ++ks) {
        const float* g = gi + ks * 98304 + base;
        ir += g[0]; iz += g[512]; inn += g[1024];
    }
#pragma unroll
    for (int ks = 0; ks < NGH; ++ks) {
        const float* g = gh + ks * 98304 + base;
        hr += g[0]; hz += g[512]; hn += g[1024];
    }
    float r = 1.f / (1.f + expf(-(ir + hr)));
    float z = 1.f / (1.f + expf(-(iz + hz)));
    float n = tanhf(inn + r * hn);
    float hv = (1.f - z) * n + z * h[i];
    h[i] = hv;
    store_plane(hH, hL, b, d, hv);
}

// ---------------------------------------------------------------------------
// S5: logits + fused per-block argmax partials. grid = 250.
// ---------------------------------------------------------------------------
__global__ __launch_bounds__(512) void k_logits(
    const char* __restrict__ hH, const char* __restrict__ hL,
    const unsigned short* __restrict__ WH, const unsigned short* __restrict__ WL,
    float* __restrict__ out, int step,
    float* __restrict__ pval, int* __restrict__ pidx)
{
    DECLARE_LDS();
    mfma_gemm<true>(hH, hL, 1024, 0,
                    WH, WL, (size_t)blockIdx.x * 8 * 8192, 8,
                    out + step * 32000, 128000, blockIdx.x * 128,
                    AsH, AsL, BsH, BsL, pval, pidx, blockIdx.x);
}

// ---------------------------------------------------------------------------
extern "C" void kernel_launch(void* const* d_in, const int* in_sizes, int n_in,
                              void* d_out, int out_size, void* d_ws, size_t ws_size,
                              hipStream_t stream)
{
    const float* hidden = (const float*)d_in[0];
    const float* in_w   = (const float*)d_in[1];
    const float* in_b   = (const float*)d_in[2];
    const float* w_ih0  = (const float*)d_in[3];
    const float* w_hh0  = (const float*)d_in[4];
    const float* b_ih0  = (const float*)d_in[5];
    const float* b_hh0  = (const float*)d_in[6];
    const float* w_ih1  = (const float*)d_in[7];
    const float* w_hh1  = (const float*)d_in[8];
    const float* b_ih1  = (const float*)d_in[9];
    const float* b_hh1  = (const float*)d_in[10];
    const float* embed  = (const float*)d_in[11];
    const float* out_w  = (const float*)d_in[12];
    float* out = (float*)d_out;                    // [64, 4, 32000]
    char*  ws  = (char*)d_ws;

    // ws layout (bytes) — ~103 MiB of 256 MiB workspace
    float* hA  = (float*)(ws + 0);                           // 131072
    float* hB  = (float*)(ws + 131072);                      // 131072
    unsigned short* hAH = (unsigned short*)(ws + 262144);    // 65536 each
    unsigned short* hAL = (unsigned short*)(ws + 327680);
    unsigned short* hBH = (unsigned short*)(ws + 393216);
    unsigned short* hBL = (unsigned short*)(ws + 458752);
    char* hidH = ws + 524288;                                // 524288
    char* hidL = ws + 1048576;                               // 524288
    float* g_gi0 = (float*)(ws + 1572864);                   // 8*393216 = 3145728
    float* g_gh0 = (float*)(ws + 4718592);                   // 3145728
    float* g_gi1 = (float*)(ws + 7864320);                   // 3145728
    float* g_gh1 = (float*)(ws + 11010048);                  // 4*393216 = 1572864
    float* pval  = (float*)(ws + 12582912);                  // 64000 (pad 65536)
    int*   pidx  = (int*)  (ws + 12648448);                  // 64000 (pad 65536)
    float* ipart = (float*)(ws + 12713984);                  // 64*131072 = 8388608
    unsigned short* owH = (unsigned short*)(ws + 21102592);  // 32768000
    unsigned short* owL = (unsigned short*)(ws + 53870592);  // 32768000
    unsigned short* gwH = (unsigned short*)(ws + 86638592);  // 6291456
    unsigned short* gwL = (unsigned short*)(ws + 92930048);  // 6291456
    unsigned short* inH = (unsigned short*)(ws + 99221504);  // 4194304
    unsigned short* inL = (unsigned short*)(ws + 103415808); // 4194304

    // ---- prologue: 3 dispatches ----
    k_split_all<<<256, 512, 0, stream>>>(out_w, w_ih0, w_hh0, w_ih1, w_hh1,
                                         in_w, hidden,
                                         owH, owL, gwH, gwL, inH, inL, hidH, hidL);
    k_inproj<<<256, 512, 0, stream>>>(hidH, hidL, inH, inL, ipart);
    k_reduce_inproj<<<64, 512, 0, stream>>>(ipart, in_b, hA, hB,
                                            hAH, hAL, hBH, hBL);

    // ---- step loop: 5 dispatches/step ----
    for (int step = 0; step < 4; ++step) {
        k_gates3<<<240, 512, 0, stream>>>(step, pval, pidx, embed,
                                          (char*)hAH, (char*)hAL,
                                          (char*)hBH, (char*)hBL,
                                          gwH, gwL, g_gi0, g_gh0, g_gh1);
        k_combine<8, 8><<<64, 512, 0, stream>>>(g_gi0, g_gh0, b_ih0, b_hh0,
                                                hA, hAH, hAL);
        k_gates1<<<96, 512, 0, stream>>>((char*)hAH, (char*)hAL, gwH, gwL, g_gi1);
        k_combine<8, 4><<<64, 512, 0, stream>>>(g_gi1, g_gh1, b_ih1, b_hh1,
                                                hB, hBH, hBL);
        k_logits<<<250, 512, 0, stream>>>((char*)hBH, (char*)hBL, owH, owL,
                                          out, step, pval, pidx);
    }
}